// Round 1
// 462.373 us; speedup vs baseline: 1.0116x; 1.0116x over previous
//
#include <hip/hip_runtime.h>

// PLIF: v[t] = zero-reset( v[t-1]*decay + x[t] ), reset at v >= 1.0.
// T=16, spatial = N*C*H*W = 4194304 elements -> 256 MiB in + 256 MiB out.
// Pure streaming kernel. v carried in registers across the T scan.
//
// This version vs. previous (467 us, ~2.5 TB/s, latency-bound):
//  - 2 independent float4 streams per thread (32 B/lane) -> 2x memory-level
//    parallelism; wave touches 2 KB contiguous per load pair.
//  - explicit software prefetch of timestep t+1 before compute/store of t,
//    so loads stay ahead of the dependent store chain.
//  - non-temporal stores: output is written once and never read; keep it
//    from evicting x from the 256 MiB LLC (x re-read across bench iters).

#define T_STEPS 16
#define V_THRESHOLD 1.0f

typedef float f32x4 __attribute__((ext_vector_type(4)));

__device__ __forceinline__ void plif_step4(f32x4& v, const f32x4 xv, const float d) {
    v.x = fmaf(v.x, d, xv.x); if (v.x >= V_THRESHOLD) v.x = 0.f;
    v.y = fmaf(v.y, d, xv.y); if (v.y >= V_THRESHOLD) v.y = 0.f;
    v.z = fmaf(v.z, d, xv.z); if (v.z >= V_THRESHOLD) v.z = 0.f;
    v.w = fmaf(v.w, d, xv.w); if (v.w >= V_THRESHOLD) v.w = 0.f;
}

__global__ __launch_bounds__(256) void plif_kernel(
    const f32x4* __restrict__ x,      // [T, SPATIAL/4]
    const float* __restrict__ decay,  // [1]
    f32x4*       __restrict__ out,    // [T, SPATIAL/4]
    long long    stride4)             // SPATIAL/4 (even)
{
    const long long base =
        ((long long)blockIdx.x * blockDim.x + threadIdx.x) * 2;
    if (base >= stride4) return;
    const float d = decay[0];

    f32x4 va = (f32x4)0.f, vb = (f32x4)0.f;
    long long off = base;

    // Prime the pipeline: loads for t=0.
    f32x4 xa = x[off];
    f32x4 xb = x[off + 1];

#pragma unroll
    for (int t = 0; t < T_STEPS; ++t) {
        f32x4 na, nb;
        if (t + 1 < T_STEPS) {
            // Issue next-timestep loads BEFORE the dependent compute+store.
            na = x[off + stride4];
            nb = x[off + stride4 + 1];
        } else {
            na = xa; nb = xb;  // dead, DCE'd
        }

        plif_step4(va, xa, d);
        plif_step4(vb, xb, d);

        __builtin_nontemporal_store(va, &out[off]);
        __builtin_nontemporal_store(vb, &out[off + 1]);

        xa = na; xb = nb;
        off += stride4;
    }
}

extern "C" void kernel_launch(void* const* d_in, const int* in_sizes, int n_in,
                              void* d_out, int out_size, void* d_ws, size_t ws_size,
                              hipStream_t stream) {
    const float* x     = (const float*)d_in[0];   // [T,N,C,H,W] fp32
    const float* decay = (const float*)d_in[1];   // [1] fp32
    float* out         = (float*)d_out;           // [T,N,C,H,W] fp32

    const long long total   = in_sizes[0];        // T * SPATIAL
    const long long spatial = total / T_STEPS;    // 4194304
    const long long stride4 = spatial / 4;        // 1048576 float4/timestep

    const int block = 256;
    const long long threads = (stride4 + 1) / 2;  // 2 float4 per thread
    const int grid  = (int)((threads + block - 1) / block);  // 2048

    plif_kernel<<<grid, block, 0, stream>>>(
        (const f32x4*)x, decay, (f32x4*)out, stride4);
}